// Round 1
// baseline (2845.292 us; speedup 1.0000x reference)
//
#include <hip/hip_runtime.h>
#include <hip/hip_bf16.h>

#define HID 128

static inline size_t align256(size_t x) { return (x + 255) & ~(size_t)255; }

// ---------------- CSR build ----------------

__global__ __launch_bounds__(256) void k_count(const int* __restrict__ dst,
                                               int* __restrict__ deg, int E) {
  int e = blockIdx.x * 256 + threadIdx.x;
  if (e < E) atomicAdd(&deg[dst[e]], 1);
}

__global__ __launch_bounds__(512) void k_block_sums(const int* __restrict__ deg,
                                                    int* __restrict__ partials, int n) {
  __shared__ int sb[512];
  int t = threadIdx.x;
  int i = blockIdx.x * 512 + t;
  sb[t] = (i < n) ? deg[i] : 0;
  __syncthreads();
  for (int s = 256; s > 0; s >>= 1) {
    if (t < s) sb[t] += sb[t + s];
    __syncthreads();
  }
  if (t == 0) partials[blockIdx.x] = sb[0];
}

// exclusive scan of partials (nparts <= 256), writes off[N] = total
__global__ __launch_bounds__(256) void k_scan_partials(int* __restrict__ partials, int nparts,
                                                       int* __restrict__ off, int N) {
  __shared__ int sb[256];
  int t = threadIdx.x;
  int v = (t < nparts) ? partials[t] : 0;
  sb[t] = v;
  __syncthreads();
  for (int o = 1; o < 256; o <<= 1) {
    int tv = (t >= o) ? sb[t - o] : 0;
    __syncthreads();
    sb[t] += tv;
    __syncthreads();
  }
  if (t < nparts) partials[t] = sb[t] - v;  // exclusive
  if (t == nparts - 1) off[N] = sb[t];      // total = E
}

__global__ __launch_bounds__(512) void k_scan_final(const int* __restrict__ deg,
                                                    const int* __restrict__ partials,
                                                    int* __restrict__ off, int n) {
  __shared__ int sb[512];
  int t = threadIdx.x;
  int i = blockIdx.x * 512 + t;
  int v = (i < n) ? deg[i] : 0;
  sb[t] = v;
  __syncthreads();
  for (int o = 1; o < 512; o <<= 1) {
    int tv = (t >= o) ? sb[t - o] : 0;
    __syncthreads();
    sb[t] += tv;
    __syncthreads();
  }
  if (i < n) off[i] = partials[blockIdx.x] + sb[t] - v;  // exclusive prefix
}

__global__ __launch_bounds__(256) void k_fill(const int* __restrict__ src,
                                              const int* __restrict__ dst,
                                              const int* __restrict__ off,
                                              int* __restrict__ cursor,
                                              int* __restrict__ srcs, int E) {
  int e = blockIdx.x * 256 + threadIdx.x;
  if (e < E) {
    int d = dst[e];
    int slot = atomicAdd(&cursor[d], 1);
    srcs[off[d] + slot] = src[e];
  }
}

// graph start offsets via binary search on sorted batch
__global__ __launch_bounds__(256) void k_goff(const int* __restrict__ batch,
                                              int* __restrict__ goff, int n, int G) {
  int g = blockIdx.x * 256 + threadIdx.x;
  if (g > G) return;
  int lo = 0, hi = n;
  while (lo < hi) {
    int mid = (lo + hi) >> 1;
    if (batch[mid] < g) lo = mid + 1; else hi = mid;
  }
  goff[g] = lo;
}

// ---------------- matmul kernels (weight-stationary in VGPRs) ----------------
// Block = 256 threads = 4 waves. Waves {0,1} -> node slot 0 (f 0..63 / 64..127),
// waves {2,3} -> node slot 1. Staging: thread t stages feature (t&127) of slot (t>>7).

// init part A: tmp[i][f] = b_comb[f] + sum_k W_comb[f][k] * emb[z[i]][k]   (k < 128)
__global__ __launch_bounds__(256) void k_init_a(const int* __restrict__ z,
                                                const float* __restrict__ emb,
                                                const float* __restrict__ W_comb,
                                                const float* __restrict__ b_comb,
                                                float* __restrict__ Y, int n) {
  __shared__ float sx[2][HID];
  const int t = threadIdx.x;
  const int wave = t >> 6, lane = t & 63;
  const int slot_c = wave >> 1;
  const int f = (wave & 1) * 64 + lane;
  const int slot_s = t >> 7, fs = t & 127;

  float wf[HID];
#pragma unroll
  for (int k4 = 0; k4 < HID / 4; ++k4) {
    const float4 wv = *(const float4*)&W_comb[f * 256 + k4 * 4];
    wf[4 * k4 + 0] = wv.x; wf[4 * k4 + 1] = wv.y; wf[4 * k4 + 2] = wv.z; wf[4 * k4 + 3] = wv.w;
  }
  const float bf = b_comb[f];

  for (int base = blockIdx.x * 2; base < n; base += gridDim.x * 2) {
    int node = base + slot_s;
    float s = 0.f;
    if (node < n) s = emb[z[node] * HID + fs];
    sx[slot_s][fs] = s;
    __syncthreads();
    int cnode = base + slot_c;
    if (cnode < n) {
      float a0 = 0.f, a1 = 0.f, a2 = 0.f, a3 = 0.f;
#pragma unroll
      for (int k4 = 0; k4 < HID / 4; ++k4) {
        const float4 xv = *(const float4*)&sx[slot_c][k4 * 4];
        a0 += wf[4 * k4 + 0] * xv.x; a1 += wf[4 * k4 + 1] * xv.y;
        a2 += wf[4 * k4 + 2] * xv.z; a3 += wf[4 * k4 + 3] * xv.w;
      }
      Y[(size_t)cnode * HID + f] = bf + ((a0 + a1) + (a2 + a3));
    }
    __syncthreads();
  }
}

// init part B: x[i][f] = relu(tmp[i][f] + sum_k W_comb[f][128+k] * pe[i][k])
__global__ __launch_bounds__(256) void k_init_b(const float* __restrict__ pos,
                                                const float* __restrict__ W_pos,
                                                const float* __restrict__ b_pos,
                                                const float* __restrict__ W_comb,
                                                const float* __restrict__ tmp,
                                                float* __restrict__ Y, int n) {
  __shared__ float sx[2][HID];
  const int t = threadIdx.x;
  const int wave = t >> 6, lane = t & 63;
  const int slot_c = wave >> 1;
  const int f = (wave & 1) * 64 + lane;
  const int slot_s = t >> 7, fs = t & 127;

  float wf[HID];
#pragma unroll
  for (int k4 = 0; k4 < HID / 4; ++k4) {
    const float4 wv = *(const float4*)&W_comb[f * 256 + 128 + k4 * 4];
    wf[4 * k4 + 0] = wv.x; wf[4 * k4 + 1] = wv.y; wf[4 * k4 + 2] = wv.z; wf[4 * k4 + 3] = wv.w;
  }

  for (int base = blockIdx.x * 2; base < n; base += gridDim.x * 2) {
    int node = base + slot_s;
    float pv = 0.f;
    if (node < n) {
      float p0 = pos[node * 3 + 0], p1 = pos[node * 3 + 1], p2 = pos[node * 3 + 2];
      pv = b_pos[fs] + W_pos[fs * 3 + 0] * p0 + W_pos[fs * 3 + 1] * p1 + W_pos[fs * 3 + 2] * p2;
    }
    sx[slot_s][fs] = pv;
    __syncthreads();
    int cnode = base + slot_c;
    if (cnode < n) {
      float a0 = 0.f, a1 = 0.f, a2 = 0.f, a3 = 0.f;
#pragma unroll
      for (int k4 = 0; k4 < HID / 4; ++k4) {
        const float4 xv = *(const float4*)&sx[slot_c][k4 * 4];
        a0 += wf[4 * k4 + 0] * xv.x; a1 += wf[4 * k4 + 1] * xv.y;
        a2 += wf[4 * k4 + 2] * xv.z; a3 += wf[4 * k4 + 3] * xv.w;
      }
      float acc = tmp[(size_t)cnode * HID + f] + ((a0 + a1) + (a2 + a3));
      Y[(size_t)cnode * HID + f] = fmaxf(acc, 0.f);
    }
    __syncthreads();
  }
}

// GIN first half: h = relu(W1 @ (x[i] + sum_{j->i} x[j]) + b1)
__global__ __launch_bounds__(256) void k_aggr_mm1(const float* __restrict__ X,
                                                  const int* __restrict__ off,
                                                  const int* __restrict__ srcs,
                                                  const float* __restrict__ W,
                                                  const float* __restrict__ bias,
                                                  float* __restrict__ Y, int n) {
  __shared__ float sx[2][HID];
  const int t = threadIdx.x;
  const int wave = t >> 6, lane = t & 63;
  const int slot_c = wave >> 1;
  const int f = (wave & 1) * 64 + lane;
  const int slot_s = t >> 7, fs = t & 127;

  float wf[HID];
#pragma unroll
  for (int k4 = 0; k4 < HID / 4; ++k4) {
    const float4 wv = *(const float4*)&W[f * HID + k4 * 4];
    wf[4 * k4 + 0] = wv.x; wf[4 * k4 + 1] = wv.y; wf[4 * k4 + 2] = wv.z; wf[4 * k4 + 3] = wv.w;
  }
  const float bf = bias[f];

  for (int base = blockIdx.x * 2; base < n; base += gridDim.x * 2) {
    int node = base + slot_s;
    float s0 = 0.f, s1 = 0.f;
    if (node < n) {
      s0 = X[(size_t)node * HID + fs];
      int e = off[node], e1 = off[node + 1];
      for (; e + 1 < e1; e += 2) {
        int sa = srcs[e], sb = srcs[e + 1];
        s0 += X[(size_t)sa * HID + fs];
        s1 += X[(size_t)sb * HID + fs];
      }
      if (e < e1) s0 += X[(size_t)srcs[e] * HID + fs];
    }
    sx[slot_s][fs] = s0 + s1;
    __syncthreads();
    int cnode = base + slot_c;
    if (cnode < n) {
      float a0 = 0.f, a1 = 0.f, a2 = 0.f, a3 = 0.f;
#pragma unroll
      for (int k4 = 0; k4 < HID / 4; ++k4) {
        const float4 xv = *(const float4*)&sx[slot_c][k4 * 4];
        a0 += wf[4 * k4 + 0] * xv.x; a1 += wf[4 * k4 + 1] * xv.y;
        a2 += wf[4 * k4 + 2] * xv.z; a3 += wf[4 * k4 + 3] * xv.w;
      }
      float acc = bf + ((a0 + a1) + (a2 + a3));
      Y[(size_t)cnode * HID + f] = fmaxf(acc, 0.f);
    }
    __syncthreads();
  }
}

// GIN second half: x = W2 @ h + b2, optional relu
__global__ __launch_bounds__(256) void k_mm2(const float* __restrict__ Xin,
                                             const float* __restrict__ W,
                                             const float* __restrict__ bias,
                                             float* __restrict__ Y, int n, int do_relu) {
  __shared__ float sx[2][HID];
  const int t = threadIdx.x;
  const int wave = t >> 6, lane = t & 63;
  const int slot_c = wave >> 1;
  const int f = (wave & 1) * 64 + lane;
  const int slot_s = t >> 7, fs = t & 127;

  float wf[HID];
#pragma unroll
  for (int k4 = 0; k4 < HID / 4; ++k4) {
    const float4 wv = *(const float4*)&W[f * HID + k4 * 4];
    wf[4 * k4 + 0] = wv.x; wf[4 * k4 + 1] = wv.y; wf[4 * k4 + 2] = wv.z; wf[4 * k4 + 3] = wv.w;
  }
  const float bf = bias[f];

  for (int base = blockIdx.x * 2; base < n; base += gridDim.x * 2) {
    int node = base + slot_s;
    float s = 0.f;
    if (node < n) s = Xin[(size_t)node * HID + fs];
    sx[slot_s][fs] = s;
    __syncthreads();
    int cnode = base + slot_c;
    if (cnode < n) {
      float a0 = 0.f, a1 = 0.f, a2 = 0.f, a3 = 0.f;
#pragma unroll
      for (int k4 = 0; k4 < HID / 4; ++k4) {
        const float4 xv = *(const float4*)&sx[slot_c][k4 * 4];
        a0 += wf[4 * k4 + 0] * xv.x; a1 += wf[4 * k4 + 1] * xv.y;
        a2 += wf[4 * k4 + 2] * xv.z; a3 += wf[4 * k4 + 3] * xv.w;
      }
      float acc = bf + ((a0 + a1) + (a2 + a3));
      if (do_relu) acc = fmaxf(acc, 0.f);
      Y[(size_t)cnode * HID + f] = acc;
    }
    __syncthreads();
  }
}

// pooling + predict MLP: out[g] = W_p2 @ relu(W_p1 @ sum_nodes x + b_p1) + b_p2
__global__ __launch_bounds__(128) void k_pool(const float* __restrict__ X,
                                              const int* __restrict__ goff,
                                              const float* __restrict__ Wp1,
                                              const float* __restrict__ bp1,
                                              const float* __restrict__ Wp2,
                                              const float* __restrict__ bp2,
                                              float* __restrict__ out, int G) {
  __shared__ float sg[HID];
  __shared__ float sred[HID];
  int g = blockIdx.x;
  int f = threadIdx.x;
  int n0 = goff[g], n1 = goff[g + 1];
  float acc = 0.f;
  for (int nn = n0; nn < n1; ++nn) acc += X[(size_t)nn * HID + f];
  sg[f] = acc;
  __syncthreads();
  float a0 = 0.f, a1 = 0.f, a2 = 0.f, a3 = 0.f;
#pragma unroll
  for (int k4 = 0; k4 < HID / 4; ++k4) {
    float4 wv = *(const float4*)&Wp1[f * HID + k4 * 4];
    float4 xv = *(const float4*)&sg[k4 * 4];
    a0 += wv.x * xv.x; a1 += wv.y * xv.y; a2 += wv.z * xv.z; a3 += wv.w * xv.w;
  }
  float h = fmaxf(bp1[f] + ((a0 + a1) + (a2 + a3)), 0.f);
  sred[f] = Wp2[f] * h;
  __syncthreads();
  for (int s = 64; s > 0; s >>= 1) {
    if (f < s) sred[f] += sred[f + s];
    __syncthreads();
  }
  if (f == 0) out[g] = sred[0] + bp2[0];
}

// ---------------- launch ----------------

extern "C" void kernel_launch(void* const* d_in, const int* in_sizes, int n_in,
                              void* d_out, int out_size, void* d_ws, size_t ws_size,
                              hipStream_t stream) {
  const int*   z      = (const int*)d_in[0];
  const float* pos    = (const float*)d_in[1];
  const int*   ei     = (const int*)d_in[2];
  const int*   batch  = (const int*)d_in[3];
  const float* emb    = (const float*)d_in[4];
  const float* W_pos  = (const float*)d_in[5];
  const float* b_pos  = (const float*)d_in[6];
  const float* W_comb = (const float*)d_in[7];
  const float* b_comb = (const float*)d_in[8];
  const float* gW1    = (const float*)d_in[9];
  const float* gb1    = (const float*)d_in[10];
  const float* gW2    = (const float*)d_in[11];
  const float* gb2    = (const float*)d_in[12];
  const float* Wp1    = (const float*)d_in[13];
  const float* bp1    = (const float*)d_in[14];
  const float* Wp2    = (const float*)d_in[15];
  const float* bp2    = (const float*)d_in[16];
  float* out = (float*)d_out;

  const int N = in_sizes[0];
  const int E = in_sizes[2] / 2;
  const int G = out_size;
  const int* srcp = ei;
  const int* dstp = ei + E;

  char* w = (char*)d_ws;
  float* A       = (float*)w; w += align256((size_t)N * HID * 4);
  float* B       = (float*)w; w += align256((size_t)N * HID * 4);
  int*   deg     = (int*)w;   w += align256((size_t)N * 4);
  int*   off     = (int*)w;   w += align256((size_t)(N + 1) * 4);
  int*   cursor  = (int*)w;   w += align256((size_t)N * 4);
  int*   srcs    = (int*)w;   w += align256((size_t)E * 4);
  int*   goff    = (int*)w;   w += align256((size_t)(G + 1) * 4);
  int*   partials= (int*)w;   w += align256(1024 * 4);

  hipMemsetAsync(deg, 0, (size_t)N * 4, stream);
  hipMemsetAsync(cursor, 0, (size_t)N * 4, stream);

  k_count<<<(E + 255) / 256, 256, 0, stream>>>(dstp, deg, E);
  int nblk = (N + 511) / 512;  // 196 for N=100000
  k_block_sums<<<nblk, 512, 0, stream>>>(deg, partials, N);
  k_scan_partials<<<1, 256, 0, stream>>>(partials, nblk, off, N);
  k_scan_final<<<nblk, 512, 0, stream>>>(deg, partials, off, N);
  k_fill<<<(E + 255) / 256, 256, 0, stream>>>(srcp, dstp, off, cursor, srcs, E);
  k_goff<<<(G + 1 + 255) / 256, 256, 0, stream>>>(batch, goff, N, G);

  k_init_a<<<2048, 256, 0, stream>>>(z, emb, W_comb, b_comb, B, N);
  k_init_b<<<2048, 256, 0, stream>>>(pos, W_pos, b_pos, W_comb, B, A, N);

  for (int i = 0; i < 3; ++i) {
    k_aggr_mm1<<<2048, 256, 0, stream>>>(A, off, srcs, gW1 + (size_t)i * HID * HID,
                                         gb1 + i * HID, B, N);
    k_mm2<<<2048, 256, 0, stream>>>(B, gW2 + (size_t)i * HID * HID, gb2 + i * HID,
                                    A, N, (i < 2) ? 1 : 0);
  }

  k_pool<<<G, HID, 0, stream>>>(A, goff, Wp1, bp1, Wp2, bp2, out, G);
}